// Round 5
// baseline (2030.831 us; speedup 1.0000x reference)
//
#include <hip/hip_runtime.h>
#include <hip/hip_bf16.h>
#include <cstdint>
#include <cstddef>

typedef __attribute__((ext_vector_type(8))) __bf16 bf16x8;
typedef __attribute__((ext_vector_type(4))) float f32x4;

__device__ __forceinline__ void gload_lds16(const void* g, void* l) {
  __builtin_amdgcn_global_load_lds(
      (__attribute__((address_space(1))) void*)(g),
      (__attribute__((address_space(3))) void*)(l),
      16, 0, 0);
}

__device__ __forceinline__ float bf2f(unsigned short u) {
  unsigned int v = ((unsigned int)u) << 16;
  return __builtin_bit_cast(float, v);
}
__device__ __forceinline__ unsigned short f2bf(float f) {
  unsigned int u = __builtin_bit_cast(unsigned int, f);
  u += 0x7fffu + ((u >> 16) & 1u);   // RNE
  return (unsigned short)(u >> 16);
}

// ---------------- elementwise / setup kernels ----------------

__global__ void cast_bf16_k(const float* __restrict__ in, unsigned short* __restrict__ out, int nv) {
  int i = blockIdx.x * blockDim.x + threadIdx.x;
  if (i < nv) {
    float4 v = ((const float4*)in)[i];
    ushort4 u;
    u.x = f2bf(v.x); u.y = f2bf(v.y); u.z = f2bf(v.z); u.w = f2bf(v.w);
    ((ushort4*)out)[i] = u;
  }
}

__global__ void coef_k(const float* __restrict__ alpha, float* __restrict__ coef) {
  int d = blockIdx.x * blockDim.x + threadIdx.x;
  if (d < 1024) coef[d] = -8.0f * log1pf(expf(alpha[d]));
}

__global__ __launch_bounds__(256) void rmsnorm_k(const float* __restrict__ x,
                                                 const float* __restrict__ w,
                                                 unsigned short* __restrict__ y) {
  const int row = blockIdx.x;
  const int tid = threadIdx.x;
  const float4 v = ((const float4*)(x + (size_t)row * 1024))[tid];
  float ss = v.x * v.x + v.y * v.y + v.z * v.z + v.w * v.w;
#pragma unroll
  for (int off = 32; off > 0; off >>= 1) ss += __shfl_down(ss, off, 64);
  __shared__ float red[4];
  if ((tid & 63) == 0) red[tid >> 6] = ss;
  __syncthreads();
  const float scale = rsqrtf((red[0] + red[1] + red[2] + red[3]) * (1.0f / 1024.0f) + 1e-6f);
  const float4 wv = ((const float4*)w)[tid];
  ushort4 u;
  u.x = f2bf(v.x * scale * wv.x);
  u.y = f2bf(v.y * scale * wv.y);
  u.z = f2bf(v.z * scale * wv.z);
  u.w = f2bf(v.w * scale * wv.w);
  ((ushort4*)(y + (size_t)row * 1024))[tid] = u;
}

// ---------------- scan kernels (L=2048 split into 16 chunks of 128) ----------------
// a is bf16; s (chunk-local scan) lives in d_out and is updated in place.

__global__ __launch_bounds__(256) void scan_p1_k(const unsigned short* __restrict__ a, float* __restrict__ s,
                                                 float* __restrict__ P, float* __restrict__ E) {
  const int b = blockIdx.z, c = blockIdx.y;
  const int d = blockIdx.x * 256 + threadIdx.x;
  size_t ix = ((size_t)b * 2048 + (size_t)c * 128) * 1024 + d;
  float prod = 1.0f, st = 0.0f;
#pragma unroll 4
  for (int t = 0; t < 128; ++t, ix += 1024) {
    const float av = bf2f(a[ix]);
    const float sv = s[ix];
    st = fmaf(av, st, sv);
    prod *= av;
    s[ix] = st;
  }
  const int oix = (b * 16 + c) * 1024 + d;
  P[oix] = prod;
  E[oix] = st;
}

__global__ __launch_bounds__(256) void scan_p2_k(const float* __restrict__ P, const float* __restrict__ E,
                                                 float* __restrict__ C) {
  const int b = blockIdx.y;
  const int d = blockIdx.x * 256 + threadIdx.x;
  float carry = 0.0f;
#pragma unroll
  for (int c = 0; c < 16; ++c) {
    const int ix = (b * 16 + c) * 1024 + d;
    C[ix] = carry;
    carry = fmaf(P[ix], carry, E[ix]);
  }
}

// NOTE: loc and hs2 ALIAS (both live in d_out) — read loc[ix] strictly before
// writing hs2[ix] at the same index; no __restrict__ on these two.
__global__ __launch_bounds__(256) void scan_p3_k(const unsigned short* __restrict__ a, const float* loc,
                                                 const float* __restrict__ C,
                                                 const unsigned short* __restrict__ gate,
                                                 const float* __restrict__ resid,
                                                 float* hs2) {
  const int b = blockIdx.z, c = blockIdx.y;
  const int d = blockIdx.x * 256 + threadIdx.x;
  float pp = C[(b * 16 + c) * 1024 + d];
  size_t ix = ((size_t)b * 2048 + (size_t)c * 128) * 1024 + d;
#pragma unroll 4
  for (int t = 0; t < 128; ++t, ix += 1024) {
    pp *= bf2f(a[ix]);
    const float o = loc[ix] + pp;
    hs2[ix] = fmaf(o, bf2f(gate[ix]), resid[ix]);
  }
}

// ---------------- fused 4-matrix GEMM + activations ----------------
// C tile 64x64, 4 waves in 2x2, each wave 32x32 per matrix, BK=32.
__global__ __launch_bounds__(256) void gemm4_act_k(
    const unsigned short* __restrict__ h,
    const unsigned short* __restrict__ Wg, const unsigned short* __restrict__ Wh,
    const unsigned short* __restrict__ Wr, const unsigned short* __restrict__ Wi,
    const float* __restrict__ bg, const float* __restrict__ bh,
    const float* __restrict__ br, const float* __restrict__ bi,
    const float* __restrict__ coef,
    unsigned short* __restrict__ gate, unsigned short* __restrict__ aout,
    float* __restrict__ sout) {
  const int K = 1024;
  __shared__ alignas(16) unsigned short As[64 * 32];
  __shared__ alignas(16) unsigned short Ws[4][64 * 32];
  const int tid = threadIdx.x, wid = tid >> 6, lane = tid & 63;
  const int mbase = blockIdx.x * 64, nbase = blockIdx.y * 64;

  f32x4 acc[4][2][2];
#pragma unroll
  for (int a1 = 0; a1 < 4; ++a1)
#pragma unroll
    for (int b1 = 0; b1 < 2; ++b1)
#pragma unroll
      for (int c1 = 0; c1 < 2; ++c1) acc[a1][b1][c1] = f32x4{0.f, 0.f, 0.f, 0.f};

  const int srow = lane >> 2;
  const int scol = (lane & 3) * 8;
  const unsigned short* aSrc = h + (size_t)(mbase + wid * 16 + srow) * K + scol;
  const unsigned short* wm = (wid == 0) ? Wg : ((wid == 1) ? Wh : ((wid == 2) ? Wr : Wi));
  const unsigned short* wSrc = wm + (size_t)(nbase + srow) * K + scol;

  const int wr = wid >> 1, wc = wid & 1;
  const int frow = lane & 15;
  const int fko = (lane >> 4) * 8;

  for (int k0 = 0; k0 < K; k0 += 32) {
    gload_lds16(aSrc + k0, &As[wid * 512]);
#pragma unroll
    for (int it = 0; it < 4; ++it)
      gload_lds16(wSrc + (size_t)(it * 16) * K + k0, &Ws[wid][it * 512]);
    __syncthreads();
    bf16x8 af[2], wf[4][2];
#pragma unroll
    for (int mi = 0; mi < 2; ++mi)
      af[mi] = *(const bf16x8*)&As[(wr * 32 + mi * 16 + frow) * 32 + fko];
#pragma unroll
    for (int mt = 0; mt < 4; ++mt)
#pragma unroll
      for (int ni = 0; ni < 2; ++ni)
        wf[mt][ni] = *(const bf16x8*)&Ws[mt][(wc * 32 + ni * 16 + frow) * 32 + fko];
#pragma unroll
    for (int mt = 0; mt < 4; ++mt)
#pragma unroll
      for (int mi = 0; mi < 2; ++mi)
#pragma unroll
        for (int ni = 0; ni < 2; ++ni)
          acc[mt][mi][ni] = __builtin_amdgcn_mfma_f32_16x16x32_bf16(af[mi], wf[mt][ni], acc[mt][mi][ni], 0, 0, 0);
    __syncthreads();
  }

  const int ccol = lane & 15, crow0 = (lane >> 4) * 4;
#pragma unroll
  for (int mi = 0; mi < 2; ++mi)
#pragma unroll
    for (int ni = 0; ni < 2; ++ni) {
      const int d = nbase + wc * 32 + ni * 16 + ccol;
      const float cg = coef[d];
      const float bgv = bg[d], bhv = bh[d], brv = br[d], biv = bi[d];
#pragma unroll
      for (int rg = 0; rg < 4; ++rg) {
        const int row = mbase + wr * 32 + mi * 16 + crow0 + rg;
        const size_t ix = (size_t)row * 1024 + d;
        const float gp = acc[0][mi][ni][rg] + bgv;
        const float hv = acc[1][mi][ni][rg] + bhv;
        const float rp = acc[2][mi][ni][rg] + brv;
        const float ip = acc[3][mi][ni][rg] + biv;
        const float gv = 0.5f * gp * (1.0f + erff(gp * 0.70710678118654752f));
        const float rv = 1.0f / (1.0f + __expf(-rp));
        const float iv = 1.0f / (1.0f + __expf(-ip));
        const float av = __expf(cg * rv);
        const float sv = sqrtf(fmaxf(0.0f, 1.0f - av * av)) * hv * iv;
        gate[ix] = f2bf(gv);
        aout[ix] = f2bf(av);
        sout[ix] = sv;
      }
    }
}

// ---------------- fused 2-matrix MLP GEMM (one 1536-col slab) ----------------
// p_slab = gelu(h2@Wg_s.T+bg_s) * (h2@Wf_s.T+bf_s); p stride 1536.
// C tile 128x64, 4 waves in 2x2, wave 64x32 per matrix, BK=32.
__global__ __launch_bounds__(256) void gemm2_mlp_k(
    const unsigned short* __restrict__ h2,
    const unsigned short* __restrict__ Wgm, const unsigned short* __restrict__ Wfm,
    const float* __restrict__ bg, const float* __restrict__ bf,
    unsigned short* __restrict__ p) {
  const int K = 1024;
  const int NP = 1536;
  __shared__ alignas(16) unsigned short As[128 * 32];
  __shared__ alignas(16) unsigned short Ws[2][64 * 32];
  const int tid = threadIdx.x, wid = tid >> 6, lane = tid & 63;
  const int mbase = blockIdx.x * 128, nbase = blockIdx.y * 64;

  f32x4 acc[2][4][2];
#pragma unroll
  for (int a1 = 0; a1 < 2; ++a1)
#pragma unroll
    for (int b1 = 0; b1 < 4; ++b1)
#pragma unroll
      for (int c1 = 0; c1 < 2; ++c1) acc[a1][b1][c1] = f32x4{0.f, 0.f, 0.f, 0.f};

  const int srow = lane >> 2;
  const int scol = (lane & 3) * 8;
  const int wr = wid >> 1, wc = wid & 1;
  const int frow = lane & 15;
  const int fko = (lane >> 4) * 8;

  for (int k0 = 0; k0 < K; k0 += 32) {
    for (int s = wid; s < 8; s += 4)
      gload_lds16(h2 + (size_t)(mbase + s * 16 + srow) * K + k0 + scol, &As[s * 512]);
    for (int t = wid; t < 8; t += 4) {
      const int mat = t >> 2, sg = t & 3;
      const unsigned short* wp = mat ? Wfm : Wgm;
      gload_lds16(wp + (size_t)(nbase + sg * 16 + srow) * K + k0 + scol, &Ws[mat][sg * 512]);
    }
    __syncthreads();
    bf16x8 af[4], wf[2][2];
#pragma unroll
    for (int mi = 0; mi < 4; ++mi)
      af[mi] = *(const bf16x8*)&As[(wr * 64 + mi * 16 + frow) * 32 + fko];
#pragma unroll
    for (int mt = 0; mt < 2; ++mt)
#pragma unroll
      for (int ni = 0; ni < 2; ++ni)
        wf[mt][ni] = *(const bf16x8*)&Ws[mt][(wc * 32 + ni * 16 + frow) * 32 + fko];
#pragma unroll
    for (int mt = 0; mt < 2; ++mt)
#pragma unroll
      for (int mi = 0; mi < 4; ++mi)
#pragma unroll
        for (int ni = 0; ni < 2; ++ni)
          acc[mt][mi][ni] = __builtin_amdgcn_mfma_f32_16x16x32_bf16(af[mi], wf[mt][ni], acc[mt][mi][ni], 0, 0, 0);
    __syncthreads();
  }

  const int ccol = lane & 15, crow0 = (lane >> 4) * 4;
#pragma unroll
  for (int mi = 0; mi < 4; ++mi)
#pragma unroll
    for (int ni = 0; ni < 2; ++ni) {
      const int n = nbase + wc * 32 + ni * 16 + ccol;
      const float bgv = bg[n], bfv = bf[n];
#pragma unroll
      for (int rg = 0; rg < 4; ++rg) {
        const int row = mbase + wr * 64 + mi * 16 + crow0 + rg;
        const float g = acc[0][mi][ni][rg] + bgv;
        const float f = acc[1][mi][ni][rg] + bfv;
        const float pv = 0.5f * g * (1.0f + erff(g * 0.70710678118654752f)) * f;
        p[(size_t)row * NP + n] = f2bf(pv);
      }
    }
}

// ---------------- final GEMM slab: io += p_slab@Wo_slab.T (+ bo on first) ----------------
// p stride 1536 (K=1536 this pass); Wo stride 3072 (pre-offset to slab).
// io is d_out: per-element read-then-write, alias-safe across both passes.
__global__ __launch_bounds__(256) void gemm_out_k(
    const unsigned short* __restrict__ p,
    const unsigned short* __restrict__ Wo,
    const float* __restrict__ bo,
    float* io, int addBias) {
  const int K = 1536;
  __shared__ alignas(16) unsigned short As[128 * 32];
  __shared__ alignas(16) unsigned short Ws2[128 * 32];
  const int tid = threadIdx.x, wid = tid >> 6, lane = tid & 63;
  const int mbase = blockIdx.x * 128, nbase = blockIdx.y * 128;

  f32x4 acc[4][4];
#pragma unroll
  for (int a1 = 0; a1 < 4; ++a1)
#pragma unroll
    for (int b1 = 0; b1 < 4; ++b1) acc[a1][b1] = f32x4{0.f, 0.f, 0.f, 0.f};

  const int srow = lane >> 2;
  const int scol = (lane & 3) * 8;
  const int wr = wid >> 1, wc = wid & 1;
  const int frow = lane & 15;
  const int fko = (lane >> 4) * 8;

  for (int k0 = 0; k0 < K; k0 += 32) {
    for (int s = wid; s < 8; s += 4) {
      gload_lds16(p + (size_t)(mbase + s * 16 + srow) * 1536 + k0 + scol, &As[s * 512]);
      gload_lds16(Wo + (size_t)(nbase + s * 16 + srow) * 3072 + k0 + scol, &Ws2[s * 512]);
    }
    __syncthreads();
    bf16x8 af[4], wf[4];
#pragma unroll
    for (int mi = 0; mi < 4; ++mi)
      af[mi] = *(const bf16x8*)&As[(wr * 64 + mi * 16 + frow) * 32 + fko];
#pragma unroll
    for (int ni = 0; ni < 4; ++ni)
      wf[ni] = *(const bf16x8*)&Ws2[(wc * 64 + ni * 16 + frow) * 32 + fko];
#pragma unroll
    for (int mi = 0; mi < 4; ++mi)
#pragma unroll
      for (int ni = 0; ni < 4; ++ni)
        acc[mi][ni] = __builtin_amdgcn_mfma_f32_16x16x32_bf16(af[mi], wf[ni], acc[mi][ni], 0, 0, 0);
    __syncthreads();
  }

  const int ccol = lane & 15, crow0 = (lane >> 4) * 4;
#pragma unroll
  for (int mi = 0; mi < 4; ++mi)
#pragma unroll
    for (int ni = 0; ni < 4; ++ni) {
      const int n = nbase + wc * 64 + ni * 16 + ccol;
      const float bov = addBias ? bo[n] : 0.0f;
#pragma unroll
      for (int rg = 0; rg < 4; ++rg) {
        const int row = mbase + wr * 64 + mi * 16 + crow0 + rg;
        const size_t ix = (size_t)row * 1024 + n;
        io[ix] = acc[mi][ni][rg] + bov + io[ix];
      }
    }
}

// ---------------- host launcher ----------------

extern "C" void kernel_launch(void* const* d_in, const int* in_sizes, int n_in,
                              void* d_out, int out_size, void* d_ws, size_t ws_size,
                              hipStream_t stream) {
  (void)in_sizes; (void)n_in; (void)out_size; (void)ws_size;
  const float* hidden  = (const float*)d_in[0];
  const float* alpha   = (const float*)d_in[1];
  const float* fc_w    = (const float*)d_in[2];
  const float* fc_b    = (const float*)d_in[3];
  const float* fc_r_w  = (const float*)d_in[4];
  const float* fc_r_b  = (const float*)d_in[5];
  const float* fc_i_w  = (const float*)d_in[6];
  const float* fc_i_b  = (const float*)d_in[7];
  const float* fc_g_w  = (const float*)d_in[8];
  const float* fc_g_b  = (const float*)d_in[9];
  const float* norm_w  = (const float*)d_in[10];
  const float* norm2_w = (const float*)d_in[11];
  const float* mg_w    = (const float*)d_in[12];
  const float* mg_b    = (const float*)d_in[13];
  const float* mf_w    = (const float*)d_in[14];
  const float* mf_b    = (const float*)d_in[15];
  const float* out_w   = (const float*)d_in[16];
  const float* out_b   = (const float*)d_in[17];
  float* out = (float*)d_out;

  const size_t BL = 32768;
  char* ws = (char*)d_ws;
  size_t off = 0;
  auto alloc = [&](size_t bytes) -> char* {
    char* r = ws + off;
    off = (off + bytes + 255) & ~(size_t)255;
    return r;
  };

  // ---- workspace layout (~221 MiB total; s / hs2 / out live in d_out) ----
  unsigned short* wg  = (unsigned short*)alloc((size_t)1024 * 1024 * 2);
  unsigned short* wh  = (unsigned short*)alloc((size_t)1024 * 1024 * 2);
  unsigned short* wr  = (unsigned short*)alloc((size_t)1024 * 1024 * 2);
  unsigned short* wi  = (unsigned short*)alloc((size_t)1024 * 1024 * 2);
  unsigned short* wmg = (unsigned short*)alloc((size_t)3072 * 1024 * 2);
  unsigned short* wmf = (unsigned short*)alloc((size_t)3072 * 1024 * 2);
  unsigned short* wo  = (unsigned short*)alloc((size_t)1024 * 3072 * 2);
  float* coef         = (float*)alloc(1024 * 4);
  unsigned short* hbf = (unsigned short*)alloc(BL * 1024 * 2);   // h, later h2 (64 MiB)
  unsigned short* gate= (unsigned short*)alloc(BL * 1024 * 2);   // 64 MiB; later p_slab head
  unsigned short* abf = (unsigned short*)alloc(BL * 1024 * 2);   // 64 MiB; later p_slab tail
  float* Pb           = (float*)alloc((size_t)16 * 16 * 1024 * 4);
  float* Eb           = (float*)alloc((size_t)16 * 16 * 1024 * 4);
  float* Cb           = (float*)alloc((size_t)16 * 16 * 1024 * 4);
  float* sbuf = (float*)d_out;          // s lives in d_out; scanned in place
  float* hs2  = (float*)d_out;          // hs2 overwrites s per-element in p3
  unsigned short* pbuf = gate;          // p_slab (96 MiB) aliases gate(64)+abf(64)

  // weight casts
  cast_bf16_k<<<1024, 256, 0, stream>>>(fc_g_w, wg, 262144);
  cast_bf16_k<<<1024, 256, 0, stream>>>(fc_w,   wh, 262144);
  cast_bf16_k<<<1024, 256, 0, stream>>>(fc_r_w, wr, 262144);
  cast_bf16_k<<<1024, 256, 0, stream>>>(fc_i_w, wi, 262144);
  cast_bf16_k<<<3072, 256, 0, stream>>>(mg_w,  wmg, 786432);
  cast_bf16_k<<<3072, 256, 0, stream>>>(mf_w,  wmf, 786432);
  cast_bf16_k<<<3072, 256, 0, stream>>>(out_w, wo,  786432);
  coef_k<<<4, 256, 0, stream>>>(alpha, coef);

  // stage 1
  rmsnorm_k<<<32768, 256, 0, stream>>>(hidden, norm_w, hbf);
  gemm4_act_k<<<dim3(512, 16), 256, 0, stream>>>(hbf, wg, wh, wr, wi,
                                                 fc_g_b, fc_b, fc_r_b, fc_i_b,
                                                 coef, gate, abf, sbuf);
  // scan
  scan_p1_k<<<dim3(4, 16, 16), 256, 0, stream>>>(abf, sbuf, Pb, Eb);
  scan_p2_k<<<dim3(4, 16), 256, 0, stream>>>(Pb, Eb, Cb);
  scan_p3_k<<<dim3(4, 16, 16), 256, 0, stream>>>(abf, sbuf, Cb, gate, hidden, hs2);

  // stage 2
  rmsnorm_k<<<32768, 256, 0, stream>>>(hs2, norm2_w, hbf);
  // slab 0: cols 0..1535
  gemm2_mlp_k<<<dim3(256, 24), 256, 0, stream>>>(hbf, wmg, wmf, mg_b, mf_b, pbuf);
  gemm_out_k<<<dim3(256, 8), 256, 0, stream>>>(pbuf, wo, out_b, out, 1);
  // slab 1: cols 1536..3071
  gemm2_mlp_k<<<dim3(256, 24), 256, 0, stream>>>(hbf, wmg + (size_t)1536 * 1024,
                                                 wmf + (size_t)1536 * 1024,
                                                 mg_b + 1536, mf_b + 1536, pbuf);
  gemm_out_k<<<dim3(256, 8), 256, 0, stream>>>(pbuf, wo + 1536, out_b, out, 0);
}